// Round 14
// baseline (239.585 us; speedup 1.0000x reference)
//
#include <hip/hip_runtime.h>
#include <math.h>

typedef _Float16 f16x8 __attribute__((ext_vector_type(8)));
typedef _Float16 f16x2 __attribute__((ext_vector_type(2)));
typedef float    f32x4 __attribute__((ext_vector_type(4)));

union F16x8u { f16x8 v; f16x2 h[4]; };

__device__ __forceinline__ float cos1_hw(float x) { return __builtin_amdgcn_cosf(x); }
__device__ __forceinline__ float sin1_hw(float x) { return __builtin_amdgcn_sinf(x); }

__device__ __forceinline__ f16x2 pkrtz(float a, float b)
{
    return __builtin_bit_cast(f16x2, __builtin_amdgcn_cvt_pkrtz(a, b));
}

// keep a 16B fragment live without DCE (consume 2 of its 4 VGPRs)
__device__ __forceinline__ void consume8h(const f16x8& x)
{
    f32x4 t = __builtin_bit_cast(f32x4, x);
    asm volatile("" :: "v"(t[0]), "v"(t[3]));
}

// ---------------------------------------------------------------------------
// ROUND 20 = RERUN of the round-19 phase ablation (round 19 died to the same
// broker/infra error as round 11's first attempt; kernel never ran).
// Six consecutive latency-theory nulls + a 3-4x model/counter mismatch =>
// measure, don't theorize. template<MODE,REPS>: MODE bit0=E1-build,
// bit1=MFMA, bit2=apply/E2. Stubbed phases stay live via asm-opaque values
// (DCE rule: ablation-via-skip deletes upstream ops). Diagnostics run REPS=2
// (>40us -> surface in top-5 with counters) and write d_ws; production
// (MODE=7, REPS=1, math identical to the 76.85us kernel) writes out, last.
// Readout: MFMA marginal = M7-M6, E1 marginal = M7-M5, apply marginal =
// M7-M3 (all rep2). Decision table in session notes.
// ---------------------------------------------------------------------------

template<int MODE, int REPS>
__global__ __launch_bounds__(1024, 4)
void fourier_k(const float* __restrict__ y,
               const float* __restrict__ xnew,
               float* __restrict__ outp)
{
    __shared__ _Float16 Yt [64 * 72];
    __shared__ _Float16 Trl[64 * 72];
    __shared__ _Float16 Til[64 * 72];
    __shared__ _Float16 FrL[64 * 72];
    __shared__ _Float16 FiL[64 * 72];
    __shared__ float2   XY[2048];
    __shared__ float2   tw[64];

    const int tid   = threadIdx.x;
    const int batch = blockIdx.x >> 3;
    const int sgrp  = blockIdx.x & 7;
    const int pbase = (batch << 14) + (sgrp << 11);

    ((float4*)XY)[tid] = ((const float4*)(xnew + ((size_t)pbase << 1)))[tid];
    {
        const float4 v = ((const float4*)(y + (batch << 12)))[tid];
        const int n1 = tid >> 4;
        const int n2 = (tid & 15) << 2;
        Yt[(n2 + 0) * 72 + n1] = (_Float16)v.x;
        Yt[(n2 + 1) * 72 + n1] = (_Float16)v.y;
        Yt[(n2 + 2) * 72 + n1] = (_Float16)v.z;
        Yt[(n2 + 3) * 72 + n1] = (_Float16)v.w;
    }
    if (tid < 64) {
        const float a = (float)tid * (1.0f / 64.0f);
        tw[tid] = make_float2(cos1_hw(a), sin1_hw(a));
    }
    __syncthreads();

    const int lane = tid & 63;
    const int wv   = tid >> 6;
    const int quad = lane >> 4;
    const int lrow = lane & 15;

    // dummy E1 fragments for MODE without bit0 (asm-opaque, built once)
    F16x8u du, dv, dw;
    if constexpr (!(MODE & 1)) {
        float t0 = (float)lane * 0.01f + 0.25f;
        asm volatile("" : "+v"(t0));
#pragma unroll
        for (int jp = 0; jp < 4; ++jp) {
            du.h[jp] = pkrtz(t0, t0 * 0.5f);
            dv.h[jp] = pkrtz(t0 * 0.25f, t0 * 0.125f);
            dw.h[jp] = pkrtz(-t0 * 0.25f, -t0 * 0.125f);
        }
    }

#pragma unroll 1
    for (int rep = 0; rep < REPS; ++rep) {
        if (rep) __syncthreads();

        // ---- DFT pass A (MFMA) ----
        {
            const int rt   = wv >> 2;
            const int ct   = wv & 3;
            const int krow = (rt << 4) + lrow;
            f32x4 Tr = (f32x4){0.f, 0.f, 0.f, 0.f};
            f32x4 Ti = (f32x4){0.f, 0.f, 0.f, 0.f};
#pragma unroll
            for (int kt = 0; kt < 2; ++kt) {
                const int n1b = (kt << 5) + (quad << 3);
                F16x8u cf, sn;
#pragma unroll
                for (int jp = 0; jp < 4; ++jp) {
                    const float2 wa = tw[(krow * (n1b + 2 * jp    )) & 63];
                    const float2 wb = tw[(krow * (n1b + 2 * jp + 1)) & 63];
                    cf.h[jp] = pkrtz(wa.x, wb.x);
                    sn.h[jp] = pkrtz(-wa.y, -wb.y);
                }
                const f16x8 yf = *(const f16x8*)&Yt[((ct << 4) + lrow) * 72 + n1b];
                Tr = __builtin_amdgcn_mfma_f32_16x16x32_f16(cf.v, yf, Tr, 0, 0, 0);
                Ti = __builtin_amdgcn_mfma_f32_16x16x32_f16(sn.v, yf, Ti, 0, 0, 0);
            }
#pragma unroll
            for (int reg = 0; reg < 4; ++reg) {
                const int k = (rt << 4) + (quad << 2) + reg;
                Trl[k * 72 + (ct << 4) + lrow] = (_Float16)Tr[reg];
                Til[k * 72 + (ct << 4) + lrow] = (_Float16)Ti[reg];
            }
        }
        __syncthreads();

        // ---- DFT pass B (MFMA) ----
        {
            const int mt2 = wv >> 2;
            const int ct2 = wv & 3;
            const int mrow = (mt2 << 4) + lrow;
            f32x4 Fr = (f32x4){0.f, 0.f, 0.f, 0.f};
            f32x4 Fi = (f32x4){0.f, 0.f, 0.f, 0.f};
#pragma unroll
            for (int kt = 0; kt < 2; ++kt) {
                const int n2b = (kt << 5) + (quad << 3);
                F16x8u cf, sf, sn;
#pragma unroll
                for (int jp = 0; jp < 4; ++jp) {
                    const float2 wa = tw[(mrow * (n2b + 2 * jp    )) & 63];
                    const float2 wb = tw[(mrow * (n2b + 2 * jp + 1)) & 63];
                    cf.h[jp] = pkrtz(wa.x, wb.x);
                    sf.h[jp] = pkrtz(wa.y, wb.y);
                    sn.h[jp] = pkrtz(-wa.y, -wb.y);
                }
                const f16x8 btr = *(const f16x8*)&Trl[((ct2 << 4) + lrow) * 72 + n2b];
                const f16x8 bti = *(const f16x8*)&Til[((ct2 << 4) + lrow) * 72 + n2b];
                Fr = __builtin_amdgcn_mfma_f32_16x16x32_f16(cf.v, btr, Fr, 0, 0, 0);
                Fr = __builtin_amdgcn_mfma_f32_16x16x32_f16(sf.v, bti, Fr, 0, 0, 0);
                Fi = __builtin_amdgcn_mfma_f32_16x16x32_f16(cf.v, bti, Fi, 0, 0, 0);
                Fi = __builtin_amdgcn_mfma_f32_16x16x32_f16(sn.v, btr, Fi, 0, 0, 0);
            }
#pragma unroll
            for (int reg = 0; reg < 4; ++reg) {
                const int m = (mt2 << 4) + (quad << 2) + reg;
                FrL[m * 72 + (ct2 << 4) + lrow] = (_Float16)Fr[reg];
                FiL[m * 72 + (ct2 << 4) + lrow] = (_Float16)Fi[reg];
            }
        }
        __syncthreads();

        // ---- hoist A-operand fragments ----
        f16x8 Ar[4][2], Ai[4][2];
#pragma unroll
        for (int nt = 0; nt < 4; ++nt)
#pragma unroll
            for (int kt = 0; kt < 2; ++kt) {
                const int off = ((nt << 4) + lrow) * 72 + (kt << 5) + (quad << 3);
                Ar[nt][kt] = *(const f16x8*)&FrL[off];
                Ai[nt][kt] = *(const f16x8*)&FiL[off];
                if constexpr (!(MODE & 2)) {      // keep hoist alive w/o MFMA
                    consume8h(Ar[nt][kt]);
                    consume8h(Ai[nt][kt]);
                }
            }

        // ---- interp ----
#pragma unroll 1
        for (int mt = 0; mt < 8; ++mt) {
            const int lpt = ((mt >> 1) << 9) + (wv << 5) + ((mt & 1) << 4);
            const float2 xv = XY[lpt + lrow];

            f32x4 Gr[4], Gi[4];
            if constexpr (MODE & 2) {
#pragma unroll
                for (int nt = 0; nt < 4; ++nt) {
                    Gr[nt] = (f32x4){0.f, 0.f, 0.f, 0.f};
                    Gi[nt] = (f32x4){0.f, 0.f, 0.f, 0.f};
                }
            } else {
                float z0 = 0.0f;                 // opaque zero: apply can't fold
                asm volatile("" : "+v"(z0));
#pragma unroll
                for (int nt = 0; nt < 4; ++nt) {
                    Gr[nt] = (f32x4){z0, z0, z0, z0};
                    Gi[nt] = (f32x4){z0, z0, z0, z0};
                }
            }

            const float cs1 = cos1_hw(xv.x);
            const float sn1 = sin1_hw(xv.x);
            const float cs1b = fmaf(cs1, cs1, -(sn1 * sn1));
            const float sn1b = 2.0f * cs1 * sn1;

#pragma unroll
            for (int kt = 0; kt < 2; ++kt) {
                F16x8u ur, ui, un;
                if constexpr (MODE & 1) {
                    const float fb = (float)((quad << 3) - (kt ? 32 : 0));
                    float th = xv.x * fb;
                    th -= floorf(th);
                    float er0 = cos1_hw(th);
                    float ei0 = sin1_hw(th);
                    float er1 = fmaf(-ei0, sn1, er0 * cs1);
                    float ei1 = fmaf( er0, sn1, ei0 * cs1);
#pragma unroll
                    for (int jp = 0; jp < 4; ++jp) {
                        ur.h[jp] = pkrtz(er0, er1);
                        ui.h[jp] = pkrtz(ei0, ei1);
                        un.h[jp] = pkrtz(-ei0, -ei1);
                        if (jp < 3) {
                            const float e0 = fmaf(-ei0, sn1b, er0 * cs1b);
                            ei0 = fmaf(er0, sn1b, ei0 * cs1b);
                            er0 = e0;
                            const float e1 = fmaf(-ei1, sn1b, er1 * cs1b);
                            ei1 = fmaf(er1, sn1b, ei1 * cs1b);
                            er1 = e1;
                        }
                    }
                } else {
                    ur = du; ui = dv; un = dw;
                }

                if constexpr (MODE & 2) {
#pragma unroll
                    for (int nt = 0; nt < 4; ++nt) {
                        Gr[nt] = __builtin_amdgcn_mfma_f32_16x16x32_f16(Ar[nt][kt], ur.v, Gr[nt], 0, 0, 0);
                        Gr[nt] = __builtin_amdgcn_mfma_f32_16x16x32_f16(Ai[nt][kt], un.v, Gr[nt], 0, 0, 0);
                        Gi[nt] = __builtin_amdgcn_mfma_f32_16x16x32_f16(Ar[nt][kt], ui.v, Gi[nt], 0, 0, 0);
                        Gi[nt] = __builtin_amdgcn_mfma_f32_16x16x32_f16(Ai[nt][kt], ur.v, Gi[nt], 0, 0, 0);
                    }
                } else {                          // keep E1 build alive w/o MFMA
                    consume8h(ur.v);
                    consume8h(ui.v);
                    consume8h(un.v);
                }
            }

            float red;
            if constexpr (MODE & 4) {
                const float cs2 = cos1_hw(xv.y);
                const float sn2 = sin1_hw(xv.y);
                float t16 = xv.y * 16.0f;
                t16 -= floorf(t16);
                const float c16 = cos1_hw(t16);
                const float s16 = sin1_hw(t16);
                const float cm32 = fmaf(c16, c16, -(s16 * s16));
                const float sm32 = -2.0f * c16 * s16;

                float thA = xv.y * (float)(quad << 2);
                thA -= floorf(thA);
                const float erA = cos1_hw(thA);
                const float eiA = sin1_hw(thA);

                float br[4], bi[4];
                br[0] = erA;                            bi[0] = eiA;
                br[1] = fmaf(-eiA, s16, erA * c16);     bi[1] = fmaf(erA, s16, eiA * c16);
                br[2] = fmaf(-eiA, sm32, erA * cm32);   bi[2] = fmaf(erA, sm32, eiA * cm32);
                br[3] = fmaf(-bi[2], s16, br[2] * c16); bi[3] = fmaf(br[2], s16, bi[2] * c16);

                red = 0.0f;
#pragma unroll
                for (int nt = 0; nt < 4; ++nt) {
                    float er = br[nt];
                    float ei = bi[nt];
#pragma unroll
                    for (int reg = 0; reg < 4; ++reg) {
                        red = fmaf(Gr[nt][reg],  er, red);
                        red = fmaf(Gi[nt][reg], -ei, red);
                        if (reg < 3) {
                            const float t2 = fmaf(-ei, sn2, er * cs2);
                            ei = fmaf(er, sn2, ei * cs2);
                            er = t2;
                        }
                    }
                }
            } else {                              // cheap consume of all acc
                red = (Gr[0][0] + Gr[1][3]) + (Gr[2][0] + Gr[3][3])
                    + (Gi[0][1] + Gi[1][2]) + (Gi[2][1] + Gi[3][2]);
            }
            red += __shfl_xor(red, 16, 64);
            red += __shfl_xor(red, 32, 64);
            if (lane < 16)
                outp[pbase + lpt + lane] = red * (1.0f / 4096.0f);
        }
    }   // rep
}

extern "C" void kernel_launch(void* const* d_in, const int* in_sizes, int n_in,
                              void* d_out, int out_size, void* d_ws, size_t ws_size,
                              hipStream_t stream)
{
    const float* y    = (const float*)d_in[0];   // [32, 64, 64]
    const float* xnew = (const float*)d_in[1];   // [32, 128, 128, 2]
    float* out        = (float*)d_out;           // [32, 128, 128]
    float* ws         = (float*)d_ws;            // scratch sink for diagnostics

    // Diagnostics (rep x2, surface in top-5 with counters), write ws:
    fourier_k<7, 2><<<256, 1024, 0, stream>>>(y, xnew, ws);  // full reference
    fourier_k<5, 2><<<256, 1024, 0, stream>>>(y, xnew, ws);  // no E1-build
    fourier_k<3, 2><<<256, 1024, 0, stream>>>(y, xnew, ws);  // no apply/E2
    fourier_k<6, 2><<<256, 1024, 0, stream>>>(y, xnew, ws);  // no MFMA
    // Production (math identical to the 76.85us kernel), writes out:
    fourier_k<7, 1><<<256, 1024, 0, stream>>>(y, xnew, out);
}

// Round 15
// 77.053 us; speedup vs baseline: 3.1094x; 3.1094x over previous
//
#include <hip/hip_runtime.h>
#include <math.h>

typedef _Float16 f16x8 __attribute__((ext_vector_type(8)));
typedef _Float16 f16x2 __attribute__((ext_vector_type(2)));
typedef float    f32x4 __attribute__((ext_vector_type(4)));

union F16x8u { f16x8 v; f16x2 h[4]; };

__device__ __forceinline__ float cos1_hw(float x) { return __builtin_amdgcn_cosf(x); }
__device__ __forceinline__ float sin1_hw(float x) { return __builtin_amdgcn_sinf(x); }

__device__ __forceinline__ f16x2 pkrtz(float a, float b)
{
    return __builtin_bit_cast(f16x2, __builtin_amdgcn_cvt_pkrtz(a, b));
}

// ---------------------------------------------------------------------------
// ROUND 21 = SPILL ELIMINATION.
// r20 ablation verdict: phase marginals are SUPER-additive (each ablated
// variant ~18-28us vs 61 full at rep2; serial-additive model predicts ~127
// total, measured 54-84) => the cost is a GLOBAL resource, not a phase.
// Counters name it: FETCH 19.5MB / WRITE 32.7MB per dispatch vs ~4.6/4.0
// expected = ~43MB of scratch SPILL traffic (r7's VALU-DFT kernel: 4.1/2.0,
// clean). launch_bounds(1024,4) caps the unified file at 128 regs/wave;
// live set (Ar/Ai 32 + Gr/Gi 32 + E1 24 + E2 ~20 + temps) exceeded it.
// Explains all 6 nulls (regalloc invisible to micro-opts), the 3x VALU
// inflation (spill moves), and the super-additivity (any phase removal
// frees registers globally).
// FIX: per-nt immediate apply. Build both kt E1 fragment sets once per mt
// (24 regs); per nt: 8 MFMAs into ONE f32x4 pair (8 regs, was 32) and apply
// at once into a per-nt partial. MFMA order per acc and apply math are
// UNCHANGED -> bit-identical output. Peak live ~100 < 128 -> no spills.
// Predicted: FETCH ~4.5MB WRITE ~2MB, kernel 30.8 -> 10-16us, dur 77 -> 55-62.
// ---------------------------------------------------------------------------

__global__ __launch_bounds__(1024, 4)
void fourier_fused(const float* __restrict__ y,
                   const float* __restrict__ xnew,
                   float* __restrict__ out)
{
    __shared__ _Float16 Yt [64 * 72];    // Y^T f16: Yt[n2][n1], pitch 72
    __shared__ _Float16 Trl[64 * 72];    // T re: Trl[k][n2]
    __shared__ _Float16 Til[64 * 72];    // T im
    __shared__ _Float16 FrL[64 * 72];    // F^T re: FrL[m][k]
    __shared__ _Float16 FiL[64 * 72];    // F^T im
    __shared__ float2   XY[2048];        // sample coords
    __shared__ float2   tw[64];          // (cos, sin)(2pi n/64)

    const int tid   = threadIdx.x;
    const int batch = blockIdx.x >> 3;
    const int sgrp  = blockIdx.x & 7;                 // 8 blocks per batch
    const int pbase = (batch << 14) + (sgrp << 11);   // 2048 points

    // ---- stage xnew + y (transposed f16) + twiddles ----
    ((float4*)XY)[tid] = ((const float4*)(xnew + ((size_t)pbase << 1)))[tid];
    {
        const float4 v = ((const float4*)(y + (batch << 12)))[tid];
        const int n1 = tid >> 4;
        const int n2 = (tid & 15) << 2;
        Yt[(n2 + 0) * 72 + n1] = (_Float16)v.x;
        Yt[(n2 + 1) * 72 + n1] = (_Float16)v.y;
        Yt[(n2 + 2) * 72 + n1] = (_Float16)v.z;
        Yt[(n2 + 3) * 72 + n1] = (_Float16)v.w;
    }
    if (tid < 64) {
        const float a = (float)tid * (1.0f / 64.0f);
        tw[tid] = make_float2(cos1_hw(a), sin1_hw(a));
    }
    __syncthreads();

    const int lane = tid & 63;
    const int wv   = tid >> 6;
    const int quad = lane >> 4;
    const int lrow = lane & 15;

    // ---- DFT pass A (MFMA): T[k][n2] = sum_n1 W[k][n1] Y[n1][n2] ----
    {
        const int rt   = wv >> 2;
        const int ct   = wv & 3;
        const int krow = (rt << 4) + lrow;
        f32x4 Tr = (f32x4){0.f, 0.f, 0.f, 0.f};
        f32x4 Ti = (f32x4){0.f, 0.f, 0.f, 0.f};
#pragma unroll
        for (int kt = 0; kt < 2; ++kt) {
            const int n1b = (kt << 5) + (quad << 3);
            F16x8u cf, sn;                  // cos, -sin  (W = c - i s)
#pragma unroll
            for (int jp = 0; jp < 4; ++jp) {
                const float2 wa = tw[(krow * (n1b + 2 * jp    )) & 63];
                const float2 wb = tw[(krow * (n1b + 2 * jp + 1)) & 63];
                cf.h[jp] = pkrtz(wa.x, wb.x);
                sn.h[jp] = pkrtz(-wa.y, -wb.y);
            }
            const f16x8 yf = *(const f16x8*)&Yt[((ct << 4) + lrow) * 72 + n1b];
            Tr = __builtin_amdgcn_mfma_f32_16x16x32_f16(cf.v, yf, Tr, 0, 0, 0);
            Ti = __builtin_amdgcn_mfma_f32_16x16x32_f16(sn.v, yf, Ti, 0, 0, 0);
        }
#pragma unroll
        for (int reg = 0; reg < 4; ++reg) {
            const int k = (rt << 4) + (quad << 2) + reg;
            Trl[k * 72 + (ct << 4) + lrow] = (_Float16)Tr[reg];
            Til[k * 72 + (ct << 4) + lrow] = (_Float16)Ti[reg];
        }
    }
    __syncthreads();

    // ---- DFT pass B (MFMA): F^T[m][k] = sum_n2 W2[m][n2] T^T[n2][k] ----
    {
        const int mt2 = wv >> 2;
        const int ct2 = wv & 3;
        const int mrow = (mt2 << 4) + lrow;
        f32x4 Fr = (f32x4){0.f, 0.f, 0.f, 0.f};
        f32x4 Fi = (f32x4){0.f, 0.f, 0.f, 0.f};
#pragma unroll
        for (int kt = 0; kt < 2; ++kt) {
            const int n2b = (kt << 5) + (quad << 3);
            F16x8u cf, sf, sn;
#pragma unroll
            for (int jp = 0; jp < 4; ++jp) {
                const float2 wa = tw[(mrow * (n2b + 2 * jp    )) & 63];
                const float2 wb = tw[(mrow * (n2b + 2 * jp + 1)) & 63];
                cf.h[jp] = pkrtz(wa.x, wb.x);
                sf.h[jp] = pkrtz(wa.y, wb.y);
                sn.h[jp] = pkrtz(-wa.y, -wb.y);
            }
            const f16x8 btr = *(const f16x8*)&Trl[((ct2 << 4) + lrow) * 72 + n2b];
            const f16x8 bti = *(const f16x8*)&Til[((ct2 << 4) + lrow) * 72 + n2b];
            Fr = __builtin_amdgcn_mfma_f32_16x16x32_f16(cf.v, btr, Fr, 0, 0, 0);
            Fr = __builtin_amdgcn_mfma_f32_16x16x32_f16(sf.v, bti, Fr, 0, 0, 0);
            Fi = __builtin_amdgcn_mfma_f32_16x16x32_f16(cf.v, bti, Fi, 0, 0, 0);
            Fi = __builtin_amdgcn_mfma_f32_16x16x32_f16(sn.v, btr, Fi, 0, 0, 0);
        }
#pragma unroll
        for (int reg = 0; reg < 4; ++reg) {
            const int m = (mt2 << 4) + (quad << 2) + reg;
            FrL[m * 72 + (ct2 << 4) + lrow] = (_Float16)Fr[reg];
            FiL[m * 72 + (ct2 << 4) + lrow] = (_Float16)Fi[reg];
        }
    }
    __syncthreads();

    // ---- hoist A-operand (F^T) fragments once per wave ----
    f16x8 Ar[4][2], Ai[4][2];
#pragma unroll
    for (int nt = 0; nt < 4; ++nt)
#pragma unroll
        for (int kt = 0; kt < 2; ++kt) {
            const int off = ((nt << 4) + lrow) * 72 + (kt << 5) + (quad << 3);
            Ar[nt][kt] = *(const f16x8*)&FrL[off];
            Ai[nt][kt] = *(const f16x8*)&FiL[off];
        }

    // ---- interp: per mt, build E1 (both kt) once; per nt: 8 MFMAs into one
    //      f32x4 pair + IMMEDIATE apply (acc live = 8 regs, was 32). ----
#pragma unroll 1
    for (int mt = 0; mt < 8; ++mt) {
        const int lpt = ((mt >> 1) << 9) + (wv << 5) + ((mt & 1) << 4);
        const float2 xv = XY[lpt + lrow];

        // E1 rotation steps
        const float cs1 = cos1_hw(xv.x);
        const float sn1 = sin1_hw(xv.x);
        const float cs1b = fmaf(cs1, cs1, -(sn1 * sn1));
        const float sn1b = 2.0f * cs1 * sn1;

        F16x8u ur0, ui0, un0, ur1, ui1, un1;
#pragma unroll
        for (int kt = 0; kt < 2; ++kt) {
            const float fb = (float)((quad << 3) - (kt ? 32 : 0));
            float th = xv.x * fb;
            th -= floorf(th);                  // revolutions in [0,1)
            float er0 = cos1_hw(th);
            float ei0 = sin1_hw(th);
            float er1 = fmaf(-ei0, sn1, er0 * cs1);
            float ei1 = fmaf( er0, sn1, ei0 * cs1);

            F16x8u& ur = kt ? ur1 : ur0;       // constant after unroll
            F16x8u& ui = kt ? ui1 : ui0;
            F16x8u& un = kt ? un1 : un0;
#pragma unroll
            for (int jp = 0; jp < 4; ++jp) {
                ur.h[jp] = pkrtz(er0, er1);
                ui.h[jp] = pkrtz(ei0, ei1);
                un.h[jp] = pkrtz(-ei0, -ei1);
                if (jp < 3) {
                    const float e0 = fmaf(-ei0, sn1b, er0 * cs1b);
                    ei0 = fmaf(er0, sn1b, ei0 * cs1b);
                    er0 = e0;
                    const float e1 = fmaf(-ei1, sn1b, er1 * cs1b);
                    ei1 = fmaf(er1, sn1b, ei1 * cs1b);
                    er1 = e1;
                }
            }
        }

        // E2 seeds (per-nt base phases by rotation, as before)
        const float cs2 = cos1_hw(xv.y);
        const float sn2 = sin1_hw(xv.y);
        float t16 = xv.y * 16.0f;
        t16 -= floorf(t16);
        const float c16 = cos1_hw(t16);
        const float s16 = sin1_hw(t16);
        const float cm32 = fmaf(c16, c16, -(s16 * s16));   // conj(rot16^2)
        const float sm32 = -2.0f * c16 * s16;

        float thA = xv.y * (float)(quad << 2);
        thA -= floorf(thA);
        const float erA = cos1_hw(thA);
        const float eiA = sin1_hw(thA);

        float br[4], bi[4];
        br[0] = erA;                            bi[0] = eiA;
        br[1] = fmaf(-eiA, s16, erA * c16);     bi[1] = fmaf(erA, s16, eiA * c16);
        br[2] = fmaf(-eiA, sm32, erA * cm32);   bi[2] = fmaf(erA, sm32, eiA * cm32);
        br[3] = fmaf(-bi[2], s16, br[2] * c16); bi[3] = fmaf(br[2], s16, bi[2] * c16);

        float red0 = 0.0f, red1 = 0.0f, red2 = 0.0f, red3 = 0.0f;
#pragma unroll
        for (int nt = 0; nt < 4; ++nt) {
            f32x4 Gr = (f32x4){0.f, 0.f, 0.f, 0.f};
            f32x4 Gi = (f32x4){0.f, 0.f, 0.f, 0.f};
            // same per-acc MFMA order as before: kt0(r,i), kt1(r,i)
            Gr = __builtin_amdgcn_mfma_f32_16x16x32_f16(Ar[nt][0], ur0.v, Gr, 0, 0, 0);
            Gr = __builtin_amdgcn_mfma_f32_16x16x32_f16(Ai[nt][0], un0.v, Gr, 0, 0, 0);
            Gr = __builtin_amdgcn_mfma_f32_16x16x32_f16(Ar[nt][1], ur1.v, Gr, 0, 0, 0);
            Gr = __builtin_amdgcn_mfma_f32_16x16x32_f16(Ai[nt][1], un1.v, Gr, 0, 0, 0);
            Gi = __builtin_amdgcn_mfma_f32_16x16x32_f16(Ar[nt][0], ui0.v, Gi, 0, 0, 0);
            Gi = __builtin_amdgcn_mfma_f32_16x16x32_f16(Ai[nt][0], ur0.v, Gi, 0, 0, 0);
            Gi = __builtin_amdgcn_mfma_f32_16x16x32_f16(Ar[nt][1], ui1.v, Gi, 0, 0, 0);
            Gi = __builtin_amdgcn_mfma_f32_16x16x32_f16(Ai[nt][1], ur1.v, Gi, 0, 0, 0);

            float er = br[nt];
            float ei = bi[nt];
            float acc = 0.0f;
#pragma unroll
            for (int reg = 0; reg < 4; ++reg) {
                acc = fmaf(Gr[reg],  er, acc);
                acc = fmaf(Gi[reg], -ei, acc);
                if (reg < 3) {
                    const float t2 = fmaf(-ei, sn2, er * cs2);
                    ei = fmaf(er, sn2, ei * cs2);
                    er = t2;
                }
            }
            if (nt == 0) red0 = acc;
            else if (nt == 1) red1 = acc;
            else if (nt == 2) red2 = acc;
            else red3 = acc;
        }
        float red = (red0 + red1) + (red2 + red3);
        red += __shfl_xor(red, 16, 64);
        red += __shfl_xor(red, 32, 64);
        if (lane < 16)
            out[pbase + lpt + lane] = red * (1.0f / 4096.0f);
    }
}

extern "C" void kernel_launch(void* const* d_in, const int* in_sizes, int n_in,
                              void* d_out, int out_size, void* d_ws, size_t ws_size,
                              hipStream_t stream)
{
    const float* y    = (const float*)d_in[0];   // [32, 64, 64]
    const float* xnew = (const float*)d_in[1];   // [32, 128, 128, 2]
    float* out        = (float*)d_out;           // [32, 128, 128]

    // ONE dispatch: 32 batches x 8 segment-groups = 256 blocks = 1 per CU.
    fourier_fused<<<256, 1024, 0, stream>>>(y, xnew, out);
}